// Round 7
// baseline (1181.658 us; speedup 1.0000x reference)
//
#include <hip/hip_runtime.h>

#define T_STEPS 10000
#define BATCH   512

__device__ __forceinline__ float fexp2(float x) {
#if __has_builtin(__builtin_amdgcn_exp2f)
  return __builtin_amdgcn_exp2f(x);
#else
  return exp2f(x);
#endif
}

__device__ __forceinline__ float frcp(float x) {
#if __has_builtin(__builtin_amdgcn_rcpf)
  return __builtin_amdgcn_rcpf(x);
#else
  return 1.0f / x;
#endif
}

// Quad-local permute: lane j of each quad receives from lane sel_j.
template <int CTRL>
__device__ __forceinline__ float qperm(float v) {
  int i = __builtin_bit_cast(int, v);
#if __has_builtin(__builtin_amdgcn_mov_dpp)
  int r = __builtin_amdgcn_mov_dpp(i, CTRL, 0xF, 0xF, true);
#else
  int r = __builtin_amdgcn_ds_swizzle(i, 0x8000 | CTRL);
#endif
  return __builtin_bit_cast(float, r);
}

// Roles in a quad (qg = tid>>2, role = tid&3); each thread carries TWO
// batch elements (2qg, 2qg+1) for static ILP — independent streams fill
// each other's latency slots on the single wave/SIMD.
//  r0: f_W/c_W | r1: f_N/c_N | r2: f_R/c_R | r3: h/0
// Scheme (validated R4-R6, absmax == exact kernel's 0.0039):
//  * main sigmoid frozen per step, midpoint-extrapolated coupling,
//    computed two steps ahead (EXT=2.5)
//  * c-sigmoid affine, refreshed every 8 steps (staged install at +2)
//  * RK4 step in closed affine form: q0 = KF*f0 + KG*G;
//    q1 = KC*c0 + e1*(LA*f0 + LB*G) + KW*VD1
__global__ __launch_bounds__(64, 1)
void sleep_rk4_kernel(const float* __restrict__ noise,
                      const float* __restrict__ pgRRe,
                      const float* __restrict__ pgRWe,
                      const float* __restrict__ pgWNi,
                      const float* __restrict__ pgWRi,
                      const float* __restrict__ pgNRi,
                      const float* __restrict__ pgNWi,
                      float* __restrict__ out)
{
  const int tid  = (int)(blockIdx.x * 64u + threadIdx.x);
  const int qg   = tid >> 2;
  const int role = tid & 3;

  const float g_RRe = *pgRRe, g_RWe = *pgRWe, g_WNi = *pgWNi;
  const float g_WRi = *pgWRi, g_NRi = *pgNRi, g_NWi = *pgNWi;

  const float L2E = 1.4426950408889634f;
  const float LN2 = 0.6931471805599453f;

  float W1, W2A, W2B, W3, NSC, BB, qa, qb, pa, pb, cs, ia, ib;
  float f0i, c0i;
  int v0i, v1i;
  bool dostore1;

  if (role == 0) {              // f_W / c_W
    const float SC = 2.0f * L2E / 0.5f;
    W1 = SC * g_NWi; W2A = SC * g_RWe; W2B = 0.0f; W3 = 0.0f; NSC = SC; BB = SC * 0.4f;
    qa = -1.0f / 1.5e6f; qb = 6.5f / 1.5e6f; pa = 0.0f; pb = -6.5f / 1.5e6f;
    cs = 2.0f * L2E / 5.0f; ia = -1.0f / 2.5e4f; ib = 1.0f / 2.5e4f;
    f0i = 6.0f; c0i = 0.9f; v0i = 0; v1i = 3; dostore1 = true;
  } else if (role == 1) {       // f_N / c_N
    const float SC = 2.0f * L2E / 0.175f;
    W1 = SC * g_WNi; W2A = 0.0f; W2B = SC * 1.5f; W3 = 0.0f; NSC = SC; BB = 0.0f;
    qa = -1.0f / 6.0e5f; qb = 5.0f / 6.0e5f; pa = 0.0f; pb = -5.0f / 6.0e5f;
    cs = 2.0f * L2E / 4.0f; ia = -1.0f / 1.0e4f; ib = 1.0f / 1.0e4f;
    f0i = 1.0e-3f; c0i = 1.0e-3f; v0i = 1; v1i = 4; dostore1 = true;
  } else if (role == 2) {       // f_R / c_R
    const float SC = 2.0f * L2E / 0.13f;
    W1 = SC * g_WRi; W2A = SC * g_NRi; W2B = 0.0f; W3 = SC * g_RRe; NSC = SC; BB = SC * 0.9f;
    qa = -1.0f / 6.0e4f; qb = 5.0f / 6.0e4f; pa = 0.0f; pb = -5.0f / 6.0e4f;
    cs = 2.0f * L2E / 2.0f; ia = -1.0f / 1.0e4f; ib = 1.0f / 1.0e4f;
    f0i = 1.0e-3f; c0i = 1.0e-3f; v0i = 2; v1i = 5; dostore1 = true;
  } else {                      // h
    W1 = 0.0f; W2A = 0.0f; W2B = -5.0f * L2E; W3 = 0.0f; NSC = 0.0f; BB = 10.0f * L2E;
    qa = -1.0f / 3.06e7f; qb = 0.0f;
    pa = (1.0f / 3.06e7f - 1.0f / 3.483e7f);
    pb = 1.0f / 3.483e7f;
    cs = 0.0f; ia = 0.0f; ib = 0.0f;
    f0i = 0.5f; c0i = 0.0f; v0i = 6; v1i = 0; dostore1 = false;
  }

  const float AQAh = 0.5f * qa, AQA1 = qa;
  const float AIAh = 0.5f * ia, AIA1 = ia;
  const float IAC  = ia * cs;
  const float TIA  = 2.0f * ia;
  const float R6   = 0.16666666666666666f;

  // ---- init: closed-form step coefficients via basis runs ----
  float vF[4], vG[4];
  auto frun = [&](float f0b, float Gb, float* v) -> float {
    const float Chb = fmaf(0.5f, Gb, f0b), C1b = f0b + Gb;
    float s0 = f0b, acc = -3.0f * f0b;
    s0 = fmaf(AQAh, s0, Chb); v[0] = s0; acc = fmaf(2.0f, s0, acc);
    s0 = fmaf(AQAh, s0, Chb); v[1] = s0; acc = fmaf(4.0f, s0, acc);
    s0 = fmaf(AQA1, s0, C1b); v[2] = s0; acc = fmaf(2.0f, s0, acc);
    s0 = fmaf(AQA1, s0, C1b); v[3] = s0; acc = fmaf(1.0f, s0, acc);
    float q = acc * R6; q = fmaf(fmaf(q, -6.0f, acc), R6, q); return q;
  };
  const float KF = frun(1.0f, 0.0f, vF);
  const float KG = frun(0.0f, 1.0f, vG);

  auto crun = [&](const float* v, float c0b, float e1u, float vd1) -> float {
    const float E1h = IAC * e1u, E11 = 2.0f * IAC * e1u;
    const float Dh = c0b + 0.5f * vd1, D1 = c0b + vd1;
    float s1 = c0b, acc = -3.0f * c0b;
    s1 = fmaf(AIAh, s1, fmaf(E1h, v[0], Dh)); acc = fmaf(2.0f, s1, acc);
    s1 = fmaf(AIAh, s1, fmaf(E1h, v[1], Dh)); acc = fmaf(4.0f, s1, acc);
    s1 = fmaf(AIA1, s1, fmaf(E11, v[2], D1)); acc = fmaf(2.0f, s1, acc);
    s1 = fmaf(AIA1, s1, fmaf(E11, v[3], D1)); acc = fmaf(1.0f, s1, acc);
    float q = acc * R6; q = fmaf(fmaf(q, -6.0f, acc), R6, q); return q;
  };
  float z4[4] = {0.0f, 0.0f, 0.0f, 0.0f};
  const float KC  = crun(z4, 1.0f, 0.0f, 0.0f);
  const float LAf = crun(vF, 0.0f, 1.0f, 0.0f);
  const float LBf = crun(vG, 0.0f, 1.0f, 0.0f);
  const float KW  = crun(z4, 0.0f, 0.0f, 1.0f);

  // ---- c-sigmoid refresh (per element; compute/install split) ----
  auto crefC = [&](float fcur, float& oLA, float& oLB, float& oVD) {
    const float zb = cs * fcur;
    const float ez = fexp2(zb);
    const float sc_ = frcp(1.0f + ez);
    const float t2 = fmaf(sc_, sc_, -sc_);
    const float e1 = LN2 * t2;
    const float vC = fmaf(-e1, zb, sc_);
    const float VD1 = fmaf(TIA, vC, ib);
    oLA = LAf * e1; oLB = LBf * e1; oVD = KW * VD1;
  };

  // ---- sigma package: G = qb + P*sigma(y(m)), m = x + 2.5*dx_prev ----
  auto doG = [&](float no_step, float dCl, float dFl, float f0l, float c0l) -> float {
    const float NBv = fmaf(NSC, no_step, BB);
    const float mc  = fmaf(2.5f, dCl, c0l);
    const float mf  = fmaf(2.5f, dFl, f0l);
    const float xA  = qperm<0x01>(mc);
    const float xBa = qperm<0x1E>(mc);
    const float xBb = qperm<0x1E>(mf);
    float Yc = fmaf(W1, xA, NBv);
    Yc = fmaf(W2A, xBa, Yc);
    Yc = fmaf(W3, mc, Yc);
    Yc = fmaf(W2B, xBb, Yc);
    const float sg = fexp2(Yc);
    const float rb = frcp(1.0f + sg);
    const float P  = fmaf(pa, f0l, pb);
    return fmaf(P, rb, qb);
  };

  // ---- per-element state (a = element 2qg, b = element 2qg+1) ----
  float f0a = f0i, c0a = c0i, dFa = 0.0f, dCa = 0.0f;
  float f0b = f0i, c0b = c0i, dFb = 0.0f, dCb = 0.0f;
  float LAa, LBa, VDa, tLAa, tLBa, tVDa;
  float LAb, LBb, VDb, tLAb, tLBb, tVDb;
  crefC(f0a, LAa, LBa, VDa);
  crefC(f0b, LAb, LBb, VDb);
  tLAa = LAa; tLBa = LBa; tVDa = VDa;
  tLAb = LAb; tLBb = LBb; tVDb = VDb;

  const float* nptr = noise + 2 * qg;
  float* ob = out + 2 * qg;
  const int o0 = v0i * BATCH, o1 = v1i * BATCH;

  float2 nb[16];
#pragma unroll
  for (int j = 0; j < 16; ++j)
    nb[j] = *(const float2*)(nptr + (size_t)j * BATCH);

  // warmup: G for steps 0,1 (no history -> d=0)
  float G0a = doG(nb[0].x, 0.0f, 0.0f, f0a, c0a);
  float G0b = doG(nb[0].y, 0.0f, 0.0f, f0b, c0b);
  float G1a = doG(nb[1].x, 0.0f, 0.0f, f0a, c0a);
  float G1b = doG(nb[1].y, 0.0f, 0.0f, f0b, c0b);

  for (int t = 0; t < T_STEPS; t += 16) {
    const int tnext = (t + 16 <= T_STEPS - 16) ? (t + 16) : (T_STEPS - 16);
    const float* __restrict__ nxt = nptr + (size_t)tnext * BATCH;
#pragma unroll
    for (int j = 0; j < 16; ++j) {
      // staged c-sigmoid refresh (off-chain)
      if ((j & 7) == 0) { crefC(f0a, tLAa, tLBa, tVDa); crefC(f0b, tLAb, tLBb, tVDb); }
      if ((j & 7) == 2) { LAa = tLAa; LBa = tLBa; VDa = tVDa;
                          LAb = tLAb; LBb = tLBb; VDb = tVDb; }

      // G for step s+2 (both elements; independent streams)
      const float2 no2 = nb[(j + 2) & 15];
      const float G2a = doG(no2.x, dCa, dFa, f0a, c0a);
      const float G2b = doG(no2.y, dCb, dFb, f0b, c0b);

      nb[j] = *(const float2*)(nxt + (size_t)j * BATCH);

      // closed-form RK4 step s (1-3 fma loop-carried chain per element)
      const float q0a = fmaf(KF, f0a, KG * G0a);
      const float q1a = fmaf(KC, c0a, fmaf(LAa, f0a, fmaf(LBa, G0a, VDa)));
      const float q0b = fmaf(KF, f0b, KG * G0b);
      const float q1b = fmaf(KC, c0b, fmaf(LAb, f0b, fmaf(LBb, G0b, VDb)));

      dFa = q0a - f0a; dCa = q1a - c0a; f0a = q0a; c0a = q1a;
      dFb = q0b - f0b; dCb = q1b - c0b; f0b = q0b; c0b = q1b;
      G0a = G1a; G1a = G2a; G0b = G1b; G1b = G2b;

      *(float2*)(ob + o0) = make_float2(q0a, q0b);
      if (dostore1) *(float2*)(ob + o1) = make_float2(q1a, q1b);
      ob += 7 * BATCH;
    }
  }
}

extern "C" void kernel_launch(void* const* d_in, const int* in_sizes, int n_in,
                              void* d_out, int out_size, void* d_ws, size_t ws_size,
                              hipStream_t stream) {
  const float* noise = (const float*)d_in[0];
  const float* gRRe  = (const float*)d_in[1];
  const float* gRWe  = (const float*)d_in[2];
  const float* gWNi  = (const float*)d_in[3];
  const float* gWRi  = (const float*)d_in[4];
  const float* gNRi  = (const float*)d_in[5];
  const float* gNWi  = (const float*)d_in[6];
  float* out = (float*)d_out;

  // 512 elements, 2 per thread, 4 lanes per element -> 1024 threads
  sleep_rk4_kernel<<<dim3((BATCH * 2) / 64), dim3(64), 0, stream>>>(
      noise, gRRe, gRWe, gWNi, gWRi, gNRi, gNWi, out);
}

// Round 8
// 641.897 us; speedup vs baseline: 1.8409x; 1.8409x over previous
//
#include <hip/hip_runtime.h>

#define T_STEPS 10000
#define BATCH   512

__device__ __forceinline__ float fexp2(float x) {
#if __has_builtin(__builtin_amdgcn_exp2f)
  return __builtin_amdgcn_exp2f(x);
#else
  return exp2f(x);
#endif
}

__device__ __forceinline__ float frcp(float x) {
#if __has_builtin(__builtin_amdgcn_rcpf)
  return __builtin_amdgcn_rcpf(x);
#else
  return 1.0f / x;
#endif
}

// Quad-local permute: lane j of each quad receives from lane sel_j.
template <int CTRL>
__device__ __forceinline__ float qperm(float v) {
  int i = __builtin_bit_cast(int, v);
#if __has_builtin(__builtin_amdgcn_mov_dpp)
  int r = __builtin_amdgcn_mov_dpp(i, CTRL, 0xF, 0xF, true);
#else
  int r = __builtin_amdgcn_ds_swizzle(i, 0x8000 | CTRL);
#endif
  return __builtin_bit_cast(float, r);
}

// Roles in a quad (b = tid>>2, role = tid&3):
//  r0: f_W/c_W | r1: f_N/c_N | r2: f_R/c_R | r3: h/0
//
// Scheme (validated R4-R7, absmax pinned at exact kernel's 0.0039):
//  * main sigmoid frozen per step, midpoint-extrapolated coupling
//  * c-sigmoid affine, 8-step refresh (staged install at +2)
//  * RK4 step in closed affine form (basis-extracted coefficients)
// New in R8: EXPLICIT 3-stage software pipeline of the G package so no
// dependent pair is closer than one iteration in program order:
//   iter s:  YcA(s+3) tree   |  e(s+2)=exp2(YcA saved)  |
//            G(s+1)=fma(P,rcp(1+e saved),qb)  |  step-map consumes G(s)
// Extrapolation EXT=3.5 slope-units (state s, dx(s-1) -> stage-mean of s+3).
__global__ __launch_bounds__(64, 1)
void sleep_rk4_kernel(const float* __restrict__ noise,
                      const float* __restrict__ pgRRe,
                      const float* __restrict__ pgRWe,
                      const float* __restrict__ pgWNi,
                      const float* __restrict__ pgWRi,
                      const float* __restrict__ pgNRi,
                      const float* __restrict__ pgNWi,
                      float* __restrict__ out,
                      float* __restrict__ ws)
{
  const int tid  = (int)(blockIdx.x * 64u + threadIdx.x);
  const int b    = tid >> 2;
  const int role = tid & 3;

  const float g_RRe = *pgRRe, g_RWe = *pgRWe, g_WNi = *pgWNi;
  const float g_WRi = *pgWRi, g_NRi = *pgNRi, g_NWi = *pgNWi;

  const float L2E = 1.4426950408889634f;
  const float LN2 = 0.6931471805599453f;

  float W1, W2A, W2B, W3, NSC, BB, qa, qb, pa, pb, cs, ia, ib;
  float f0, c0;
  int v0i, v1i;
  bool dostore1;

  if (role == 0) {              // f_W / c_W
    const float SC = 2.0f * L2E / 0.5f;
    W1 = SC * g_NWi; W2A = SC * g_RWe; W2B = 0.0f; W3 = 0.0f; NSC = SC; BB = SC * 0.4f;
    qa = -1.0f / 1.5e6f; qb = 6.5f / 1.5e6f; pa = 0.0f; pb = -6.5f / 1.5e6f;
    cs = 2.0f * L2E / 5.0f; ia = -1.0f / 2.5e4f; ib = 1.0f / 2.5e4f;
    f0 = 6.0f; c0 = 0.9f; v0i = 0; v1i = 3; dostore1 = true;
  } else if (role == 1) {       // f_N / c_N
    const float SC = 2.0f * L2E / 0.175f;
    W1 = SC * g_WNi; W2A = 0.0f; W2B = SC * 1.5f; W3 = 0.0f; NSC = SC; BB = 0.0f;
    qa = -1.0f / 6.0e5f; qb = 5.0f / 6.0e5f; pa = 0.0f; pb = -5.0f / 6.0e5f;
    cs = 2.0f * L2E / 4.0f; ia = -1.0f / 1.0e4f; ib = 1.0f / 1.0e4f;
    f0 = 1.0e-3f; c0 = 1.0e-3f; v0i = 1; v1i = 4; dostore1 = true;
  } else if (role == 2) {       // f_R / c_R
    const float SC = 2.0f * L2E / 0.13f;
    W1 = SC * g_WRi; W2A = SC * g_NRi; W2B = 0.0f; W3 = SC * g_RRe; NSC = SC; BB = SC * 0.9f;
    qa = -1.0f / 6.0e4f; qb = 5.0f / 6.0e4f; pa = 0.0f; pb = -5.0f / 6.0e4f;
    cs = 2.0f * L2E / 2.0f; ia = -1.0f / 1.0e4f; ib = 1.0f / 1.0e4f;
    f0 = 1.0e-3f; c0 = 1.0e-3f; v0i = 2; v1i = 5; dostore1 = true;
  } else {                      // h
    W1 = 0.0f; W2A = 0.0f; W2B = -5.0f * L2E; W3 = 0.0f; NSC = 0.0f; BB = 10.0f * L2E;
    qa = -1.0f / 3.06e7f; qb = 0.0f;
    pa = (1.0f / 3.06e7f - 1.0f / 3.483e7f);
    pb = 1.0f / 3.483e7f;
    cs = 0.0f; ia = 0.0f; ib = 0.0f;
    f0 = 0.5f; c0 = 0.0f; v0i = 6; v1i = 0; dostore1 = false;
  }

  const float AQAh = 0.5f * qa, AQA1 = qa;
  const float AIAh = 0.5f * ia, AIA1 = ia;
  const float IAC  = ia * cs;
  const float TIA  = 2.0f * ia;
  const float R6   = 0.16666666666666666f;

  // ---- init: closed-form step coefficients via basis runs ----
  float vF[4], vG[4];
  auto frun = [&](float f0b, float Gb, float* v) -> float {
    const float Chb = fmaf(0.5f, Gb, f0b), C1b = f0b + Gb;
    float s0 = f0b, acc = -3.0f * f0b;
    s0 = fmaf(AQAh, s0, Chb); v[0] = s0; acc = fmaf(2.0f, s0, acc);
    s0 = fmaf(AQAh, s0, Chb); v[1] = s0; acc = fmaf(4.0f, s0, acc);
    s0 = fmaf(AQA1, s0, C1b); v[2] = s0; acc = fmaf(2.0f, s0, acc);
    s0 = fmaf(AQA1, s0, C1b); v[3] = s0; acc = fmaf(1.0f, s0, acc);
    float q = acc * R6; q = fmaf(fmaf(q, -6.0f, acc), R6, q); return q;
  };
  const float KF = frun(1.0f, 0.0f, vF);
  const float KG = frun(0.0f, 1.0f, vG);

  auto crun = [&](const float* v, float c0b, float e1u, float vd1) -> float {
    const float E1h = IAC * e1u, E11 = 2.0f * IAC * e1u;
    const float Dh = c0b + 0.5f * vd1, D1 = c0b + vd1;
    float s1 = c0b, acc = -3.0f * c0b;
    s1 = fmaf(AIAh, s1, fmaf(E1h, v[0], Dh)); acc = fmaf(2.0f, s1, acc);
    s1 = fmaf(AIAh, s1, fmaf(E1h, v[1], Dh)); acc = fmaf(4.0f, s1, acc);
    s1 = fmaf(AIA1, s1, fmaf(E11, v[2], D1)); acc = fmaf(2.0f, s1, acc);
    s1 = fmaf(AIA1, s1, fmaf(E11, v[3], D1)); acc = fmaf(1.0f, s1, acc);
    float q = acc * R6; q = fmaf(fmaf(q, -6.0f, acc), R6, q); return q;
  };
  float z4[4] = {0.0f, 0.0f, 0.0f, 0.0f};
  const float KC  = crun(z4, 1.0f, 0.0f, 0.0f);
  const float LAf = crun(vF, 0.0f, 1.0f, 0.0f);
  const float LBf = crun(vG, 0.0f, 1.0f, 0.0f);
  const float KW  = crun(z4, 0.0f, 0.0f, 1.0f);

  // ---- c-sigmoid refresh (compute/install split, off-chain) ----
  float LAe, LBe, VDK, tLAe, tLBe, tVDK;
  auto crefresh_compute = [&](float fcur) {
    const float zb = cs * fcur;
    const float ez = fexp2(zb);
    const float sc_ = frcp(1.0f + ez);
    const float t2 = fmaf(sc_, sc_, -sc_);
    const float e1 = LN2 * t2;
    const float vC = fmaf(-e1, zb, sc_);
    const float VD1 = fmaf(TIA, vC, ib);
    tLAe = LAf * e1; tLBe = LBf * e1; tVDK = KW * VD1;
  };
  crefresh_compute(f0);
  LAe = tLAe; LBe = tLBe; VDK = tVDK;

  // ---- Yc tree for a given noise and coupling snapshot ----
  auto YcOf = [&](float no_step, float mcv, float mfv) -> float {
    const float NBv = fmaf(NSC, no_step, BB);
    const float xA  = qperm<0x01>(mcv);
    const float xBa = qperm<0x1E>(mcv);
    const float xBb = qperm<0x1E>(mfv);
    float Yc = fmaf(W3, mcv, NBv);
    Yc = fmaf(W2A, xBa, Yc);
    Yc = fmaf(W1, xA, Yc);
    Yc = fmaf(W2B, xBb, Yc);
    return Yc;
  };

  float dF = 0.0f, dC = 0.0f;

  const float* nptr = noise + b;
  float* ob0 = out + v0i * BATCH + b;
  float* ob1 = dostore1 ? (out + v1i * BATCH + b) : (ws + b);
  const int adv1 = dostore1 ? 7 * BATCH : 0;

  float nb[16];
#pragma unroll
  for (int j = 0; j < 16; ++j) nb[j] = nptr[(size_t)j * BATCH];

  // ---- pipeline prefill (frozen state, dx=0: steps 0..2 exact-frozen) ----
  const float Pw = fmaf(pa, f0, pb);
  float G_cur = fmaf(Pw, frcp(1.0f + fexp2(YcOf(nb[0], c0, f0))), qb); // G(0)
  float e_pip = fexp2(YcOf(nb[1], c0, f0));                            // e(1)
  float Yc_pip = YcOf(nb[2], c0, f0);                                  // Yc(2)

  for (int t = 0; t < T_STEPS; t += 16) {
    const int tnext = (t + 16 <= T_STEPS - 16) ? (t + 16) : (T_STEPS - 16);
    const float* __restrict__ nxt = nptr + (size_t)tnext * BATCH;
#pragma unroll
    for (int j = 0; j < 16; ++j) {
      // staged c-sigmoid refresh (compile-time branch; 2 iters of slack)
      if ((j & 7) == 0) crefresh_compute(f0);
      if ((j & 7) == 2) { LAe = tLAe; LBe = tLBe; VDK = tVDK; }

      // stage A: Yc for step s+3 (state s, slope dx(s-1), EXT=3.5)
      const float no3 = nb[(j + 3) & 15];
      const float mc  = fmaf(3.5f, dC, c0);
      const float mf  = fmaf(3.5f, dF, f0);
      const float Ycn = YcOf(no3, mc, mf);

      // stage B: exp for step s+2 (Yc saved one iteration ago)
      const float e_new = fexp2(Yc_pip);

      // stage C: finalize G for step s+1 (e saved one iteration ago)
      const float rb = frcp(1.0f + e_pip);
      const float P  = fmaf(pa, f0, pb);
      const float G_new = fmaf(P, rb, qb);

      // ring refill (consumed 13 iterations later)
      nb[j] = nxt[(size_t)j * BATCH];

      // step-map (step s; consumes G finalized one iteration ago)
      const float q0 = fmaf(KF, f0, KG * G_cur);
      const float q1 = fmaf(KC, c0, fmaf(LAe, f0, fmaf(LBe, G_cur, VDK)));
      dF = q0 - f0; dC = q1 - c0;
      f0 = q0; c0 = q1;
      G_cur = G_new; e_pip = e_new; Yc_pip = Ycn;

      ob0[0] = q0;
      ob1[0] = q1;
      ob0 += 7 * BATCH;
      ob1 += adv1;
    }
  }
}

extern "C" void kernel_launch(void* const* d_in, const int* in_sizes, int n_in,
                              void* d_out, int out_size, void* d_ws, size_t ws_size,
                              hipStream_t stream) {
  const float* noise = (const float*)d_in[0];
  const float* gRRe  = (const float*)d_in[1];
  const float* gRWe  = (const float*)d_in[2];
  const float* gWNi  = (const float*)d_in[3];
  const float* gWRi  = (const float*)d_in[4];
  const float* gNRi  = (const float*)d_in[5];
  const float* gNWi  = (const float*)d_in[6];
  float* out = (float*)d_out;
  float* ws  = (float*)d_ws;

  sleep_rk4_kernel<<<dim3((BATCH * 4) / 64), dim3(64), 0, stream>>>(
      noise, gRRe, gRWe, gWNi, gWRi, gNRi, gNWi, out, ws);
}

// Round 9
// 615.183 us; speedup vs baseline: 1.9208x; 1.0434x over previous
//
#include <hip/hip_runtime.h>

#define T_STEPS 10000
#define BATCH   512

__device__ __forceinline__ float fexp2(float x) {
#if __has_builtin(__builtin_amdgcn_exp2f)
  return __builtin_amdgcn_exp2f(x);
#else
  return exp2f(x);
#endif
}

__device__ __forceinline__ float frcp(float x) {
#if __has_builtin(__builtin_amdgcn_rcpf)
  return __builtin_amdgcn_rcpf(x);
#else
  return 1.0f / x;
#endif
}

// Quad-local permute: lane j of each quad receives from lane sel_j.
template <int CTRL>
__device__ __forceinline__ float qperm(float v) {
  int i = __builtin_bit_cast(int, v);
#if __has_builtin(__builtin_amdgcn_mov_dpp)
  int r = __builtin_amdgcn_mov_dpp(i, CTRL, 0xF, 0xF, true);
#else
  int r = __builtin_amdgcn_ds_swizzle(i, 0x8000 | CTRL);
#endif
  return __builtin_bit_cast(float, r);
}

// Roles in a quad (b = tid>>2, role = tid&3):
//  r0: f_W/c_W | r1: f_N/c_N | r2: f_R/c_R | r3: h/0
// Scheme (validated R4-R8, absmax pinned at exact kernel's 0.0039):
//  * main sigmoid frozen per step, midpoint-extrapolated coupling (EXT=3.5)
//  * c-sigmoid affine, 8-step refresh (staged install at +2)
//  * RK4 step in closed affine form (basis-extracted coefficients)
//  * 3-stage software pipeline of the G package (R8)
// New in R9: noise loads removed from the iteration body — 16 loads burst
// at block top into a double buffer (all static indices). No load-use pair
// closer than 13 iterations; one coarse vmcnt wait per block instead of
// per-iteration waits interleaved with stores.
__global__ __launch_bounds__(64, 1)
void sleep_rk4_kernel(const float* __restrict__ noise,
                      const float* __restrict__ pgRRe,
                      const float* __restrict__ pgRWe,
                      const float* __restrict__ pgWNi,
                      const float* __restrict__ pgWRi,
                      const float* __restrict__ pgNRi,
                      const float* __restrict__ pgNWi,
                      float* __restrict__ out,
                      float* __restrict__ ws)
{
  const int tid  = (int)(blockIdx.x * 64u + threadIdx.x);
  const int b    = tid >> 2;
  const int role = tid & 3;

  const float g_RRe = *pgRRe, g_RWe = *pgRWe, g_WNi = *pgWNi;
  const float g_WRi = *pgWRi, g_NRi = *pgNRi, g_NWi = *pgNWi;

  const float L2E = 1.4426950408889634f;
  const float LN2 = 0.6931471805599453f;

  float W1, W2A, W2B, W3, NSC, BB, qa, qb, pa, pb, cs, ia, ib;
  float f0, c0;
  int v0i, v1i;
  bool dostore1;

  if (role == 0) {              // f_W / c_W
    const float SC = 2.0f * L2E / 0.5f;
    W1 = SC * g_NWi; W2A = SC * g_RWe; W2B = 0.0f; W3 = 0.0f; NSC = SC; BB = SC * 0.4f;
    qa = -1.0f / 1.5e6f; qb = 6.5f / 1.5e6f; pa = 0.0f; pb = -6.5f / 1.5e6f;
    cs = 2.0f * L2E / 5.0f; ia = -1.0f / 2.5e4f; ib = 1.0f / 2.5e4f;
    f0 = 6.0f; c0 = 0.9f; v0i = 0; v1i = 3; dostore1 = true;
  } else if (role == 1) {       // f_N / c_N
    const float SC = 2.0f * L2E / 0.175f;
    W1 = SC * g_WNi; W2A = 0.0f; W2B = SC * 1.5f; W3 = 0.0f; NSC = SC; BB = 0.0f;
    qa = -1.0f / 6.0e5f; qb = 5.0f / 6.0e5f; pa = 0.0f; pb = -5.0f / 6.0e5f;
    cs = 2.0f * L2E / 4.0f; ia = -1.0f / 1.0e4f; ib = 1.0f / 1.0e4f;
    f0 = 1.0e-3f; c0 = 1.0e-3f; v0i = 1; v1i = 4; dostore1 = true;
  } else if (role == 2) {       // f_R / c_R
    const float SC = 2.0f * L2E / 0.13f;
    W1 = SC * g_WRi; W2A = SC * g_NRi; W2B = 0.0f; W3 = SC * g_RRe; NSC = SC; BB = SC * 0.9f;
    qa = -1.0f / 6.0e4f; qb = 5.0f / 6.0e4f; pa = 0.0f; pb = -5.0f / 6.0e4f;
    cs = 2.0f * L2E / 2.0f; ia = -1.0f / 1.0e4f; ib = 1.0f / 1.0e4f;
    f0 = 1.0e-3f; c0 = 1.0e-3f; v0i = 2; v1i = 5; dostore1 = true;
  } else {                      // h
    W1 = 0.0f; W2A = 0.0f; W2B = -5.0f * L2E; W3 = 0.0f; NSC = 0.0f; BB = 10.0f * L2E;
    qa = -1.0f / 3.06e7f; qb = 0.0f;
    pa = (1.0f / 3.06e7f - 1.0f / 3.483e7f);
    pb = 1.0f / 3.483e7f;
    cs = 0.0f; ia = 0.0f; ib = 0.0f;
    f0 = 0.5f; c0 = 0.0f; v0i = 6; v1i = 0; dostore1 = false;
  }

  const float AQAh = 0.5f * qa, AQA1 = qa;
  const float AIAh = 0.5f * ia, AIA1 = ia;
  const float IAC  = ia * cs;
  const float TIA  = 2.0f * ia;
  const float R6   = 0.16666666666666666f;

  // ---- init: closed-form step coefficients via basis runs ----
  float vF[4], vG[4];
  auto frun = [&](float f0b, float Gb, float* v) -> float {
    const float Chb = fmaf(0.5f, Gb, f0b), C1b = f0b + Gb;
    float s0 = f0b, acc = -3.0f * f0b;
    s0 = fmaf(AQAh, s0, Chb); v[0] = s0; acc = fmaf(2.0f, s0, acc);
    s0 = fmaf(AQAh, s0, Chb); v[1] = s0; acc = fmaf(4.0f, s0, acc);
    s0 = fmaf(AQA1, s0, C1b); v[2] = s0; acc = fmaf(2.0f, s0, acc);
    s0 = fmaf(AQA1, s0, C1b); v[3] = s0; acc = fmaf(1.0f, s0, acc);
    float q = acc * R6; q = fmaf(fmaf(q, -6.0f, acc), R6, q); return q;
  };
  const float KF = frun(1.0f, 0.0f, vF);
  const float KG = frun(0.0f, 1.0f, vG);

  auto crun = [&](const float* v, float c0b, float e1u, float vd1) -> float {
    const float E1h = IAC * e1u, E11 = 2.0f * IAC * e1u;
    const float Dh = c0b + 0.5f * vd1, D1 = c0b + vd1;
    float s1 = c0b, acc = -3.0f * c0b;
    s1 = fmaf(AIAh, s1, fmaf(E1h, v[0], Dh)); acc = fmaf(2.0f, s1, acc);
    s1 = fmaf(AIAh, s1, fmaf(E1h, v[1], Dh)); acc = fmaf(4.0f, s1, acc);
    s1 = fmaf(AIA1, s1, fmaf(E11, v[2], D1)); acc = fmaf(2.0f, s1, acc);
    s1 = fmaf(AIA1, s1, fmaf(E11, v[3], D1)); acc = fmaf(1.0f, s1, acc);
    float q = acc * R6; q = fmaf(fmaf(q, -6.0f, acc), R6, q); return q;
  };
  float z4[4] = {0.0f, 0.0f, 0.0f, 0.0f};
  const float KC  = crun(z4, 1.0f, 0.0f, 0.0f);
  const float LAf = crun(vF, 0.0f, 1.0f, 0.0f);
  const float LBf = crun(vG, 0.0f, 1.0f, 0.0f);
  const float KW  = crun(z4, 0.0f, 0.0f, 1.0f);

  // ---- c-sigmoid refresh (compute/install split, off-chain) ----
  float LAe, LBe, VDK, tLAe, tLBe, tVDK;
  auto crefresh_compute = [&](float fcur) {
    const float zb = cs * fcur;
    const float ez = fexp2(zb);
    const float sc_ = frcp(1.0f + ez);
    const float t2 = fmaf(sc_, sc_, -sc_);
    const float e1 = LN2 * t2;
    const float vC = fmaf(-e1, zb, sc_);
    const float VD1 = fmaf(TIA, vC, ib);
    tLAe = LAf * e1; tLBe = LBf * e1; tVDK = KW * VD1;
  };
  crefresh_compute(f0);
  LAe = tLAe; LBe = tLBe; VDK = tVDK;

  // ---- Yc tree for a given noise and coupling snapshot ----
  auto YcOf = [&](float no_step, float mcv, float mfv) -> float {
    const float NBv = fmaf(NSC, no_step, BB);
    const float xA  = qperm<0x01>(mcv);
    const float xBa = qperm<0x1E>(mcv);
    const float xBb = qperm<0x1E>(mfv);
    float Yc = fmaf(W3, mcv, NBv);
    Yc = fmaf(W2A, xBa, Yc);
    Yc = fmaf(W1, xA, Yc);
    Yc = fmaf(W2B, xBb, Yc);
    return Yc;
  };

  float dF = 0.0f, dC = 0.0f;

  const float* nptr = noise + b;
  float* ob0 = out + v0i * BATCH + b;
  float* ob1 = dostore1 ? (out + v1i * BATCH + b) : (ws + b);
  const int adv1 = dostore1 ? 7 * BATCH : 0;

  float nbA[16], nbB[16];
#pragma unroll
  for (int j = 0; j < 16; ++j) nbA[j] = nptr[(size_t)j * BATCH];

  // ---- pipeline prefill (frozen state, dx=0) ----
  const float Pw = fmaf(pa, f0, pb);
  float G_cur = fmaf(Pw, frcp(1.0f + fexp2(YcOf(nbA[0], c0, f0))), qb); // G(0)
  float e_pip = fexp2(YcOf(nbA[1], c0, f0));                            // e(1)
  float Yc_pip = YcOf(nbA[2], c0, f0);                                  // Yc(2)

  // One 16-step block: consume nbC (steps tblk..tblk+15), burst-load nbN
  // (steps tl..tl+15). All indices literal -> registers only.
#define BLOCK(nbC, nbN, tl)                                                   \
  do {                                                                        \
    const float* __restrict__ lp = nptr + (size_t)(tl) * BATCH;               \
    _Pragma("unroll")                                                         \
    for (int j = 0; j < 16; ++j) nbN[j] = lp[(size_t)j * BATCH];              \
    _Pragma("unroll")                                                         \
    for (int j = 0; j < 16; ++j) {                                            \
      if ((j & 7) == 0) crefresh_compute(f0);                                 \
      if ((j & 7) == 2) { LAe = tLAe; LBe = tLBe; VDK = tVDK; }               \
      const float no3 = (j < 13) ? nbC[(j + 3) & 15] : nbN[(j - 13) & 15];    \
      const float mc  = fmaf(3.5f, dC, c0);                                   \
      const float mf  = fmaf(3.5f, dF, f0);                                   \
      const float Ycn = YcOf(no3, mc, mf);                                    \
      const float e_new = fexp2(Yc_pip);                                      \
      const float rb = frcp(1.0f + e_pip);                                    \
      const float P  = fmaf(pa, f0, pb);                                      \
      const float G_new = fmaf(P, rb, qb);                                    \
      const float q0 = fmaf(KF, f0, KG * G_cur);                              \
      const float q1 = fmaf(KC, c0, fmaf(LAe, f0, fmaf(LBe, G_cur, VDK)));    \
      dF = q0 - f0; dC = q1 - c0;                                             \
      f0 = q0; c0 = q1;                                                       \
      G_cur = G_new; e_pip = e_new; Yc_pip = Ycn;                             \
      ob0[0] = q0;                                                            \
      ob1[0] = q1;                                                            \
      ob0 += 7 * BATCH;                                                       \
      ob1 += adv1;                                                            \
    }                                                                         \
  } while (0)

  // 312 double-blocks: steps 0..9983; final block: steps 9984..9999
  for (int t = 0; t + 32 <= T_STEPS; t += 32) {
    const int tl2 = (t + 32 <= T_STEPS - 16) ? (t + 32) : (T_STEPS - 16);
    BLOCK(nbA, nbB, t + 16);
    BLOCK(nbB, nbA, tl2);
  }
  BLOCK(nbA, nbB, T_STEPS - 16);   // final 16 steps; reload clamp (harmless)
#undef BLOCK
}

extern "C" void kernel_launch(void* const* d_in, const int* in_sizes, int n_in,
                              void* d_out, int out_size, void* d_ws, size_t ws_size,
                              hipStream_t stream) {
  const float* noise = (const float*)d_in[0];
  const float* gRRe  = (const float*)d_in[1];
  const float* gRWe  = (const float*)d_in[2];
  const float* gWNi  = (const float*)d_in[3];
  const float* gWRi  = (const float*)d_in[4];
  const float* gNRi  = (const float*)d_in[5];
  const float* gNWi  = (const float*)d_in[6];
  float* out = (float*)d_out;
  float* ws  = (float*)d_ws;

  sleep_rk4_kernel<<<dim3((BATCH * 4) / 64), dim3(64), 0, stream>>>(
      noise, gRRe, gRWe, gWNi, gWRi, gNRi, gNWi, out, ws);
}